// Round 11
// baseline (106605.774 us; speedup 1.0000x reference)
//
#include <hip/hip_runtime.h>
#include <hip/hip_bf16.h>
#include <cstdint>

#define T_STEPS 8192
#define NSCAN 32          // scan roles (goal: all on one XCD)
#define NLAUNCH 256       // launched blocks; 1/CU forced by LDS+threads

typedef unsigned long long ull;

__device__ __forceinline__ float fast_sigmoid(float v) {
  return __fdividef(1.f, 1.f + __expf(-v));
}
__device__ __forceinline__ float fast_tanh(float v) {
  return 1.f - __fdividef(2.f, __expf(2.f * v) + 1.f);
}
__device__ __forceinline__ ull packpair(float v, unsigned tag) {
  return ((ull)__float_as_uint(v) << 32) | (ull)tag;
}
__device__ __forceinline__ float bf_lo(unsigned u) { return __uint_as_float(u << 16); }
__device__ __forceinline__ float bf_hi(unsigned u) { return __uint_as_float(u & 0xFFFF0000u); }

// sc0 = L1-bypassing, serviced by the XCD's shared L2 (writeback). Within one
// XCD this is coherent cross-CU sync at ~L2 latency. Cross-XCD it can spin on
// a stale line -> handled by the sticky agent-scope fallback below.
__device__ __forceinline__ ull load_l2(const ull* p) {
  ull r;
  asm volatile("global_load_dwordx2 %0, %1, off sc0\n\ts_waitcnt vmcnt(0)"
               : "=v"(r) : "v"(p) : "memory");
  return r;
}
__device__ __forceinline__ void store_l2(ull* p, ull v) {
  asm volatile("global_store_dwordx2 %0, %1, off sc0" :: "v"(p), "v"(v) : "memory");
}
__device__ __forceinline__ int get_xcc_id() {
  int x;
  asm volatile("s_getreg_b32 %0, hwreg(HW_REG_XCC_ID)" : "=s"(x));
  return x & 15;
}

// ---------- grouped linear (8 groups of 64x64) + relu, one block per row ----------
__global__ __launch_bounds__(256) void k_grouped_relu(const float* __restrict__ in,
                                                      const float* __restrict__ W,
                                                      float* __restrict__ out) {
  __shared__ float es[512];
  const int t = blockIdx.x;
  const int tid = threadIdx.x;
  const float* inr = in + (size_t)t * 512;
  ((float2*)es)[tid] = ((const float2*)inr)[tid];
  __syncthreads();
#pragma unroll
  for (int rep = 0; rep < 2; ++rep) {
    int jj = tid + rep * 256;
    int g = jj >> 6, o = jj & 63;
    const float* wp = W + (g << 12) + o;   // W[g][i][o], stride 64 over i
    const float* ep = es + (g << 6);
    float acc = 0.f;
#pragma unroll 8
    for (int i = 0; i < 64; ++i) acc = fmaf(ep[i], wp[i << 6], acc);
    out[(size_t)t * 512 + jj] = fmaxf(acc, 0.f);
  }
}

// ---------- C[M,N] = A[M,512] * B[N,512]^T + bias[N] (+ add[M,N]) ----------
__global__ __launch_bounds__(256) void k_gemm_rr(const float* __restrict__ A,
                                                 const float* __restrict__ B,
                                                 const float* __restrict__ bias,
                                                 const float* __restrict__ add,
                                                 float* __restrict__ C, int N) {
  __shared__ float As[64][68];  // [k][m]
  __shared__ float Bs[64][68];  // [k][n]
  const int bm = blockIdx.x << 6, bn = blockIdx.y << 6;
  const int tid = threadIdx.x;
  const int tx = tid & 15, ty = tid >> 4;
  float acc[4][4] = {};
  for (int k0 = 0; k0 < 512; k0 += 64) {
#pragma unroll
    for (int u = 0; u < 4; ++u) {
      int f4 = (u << 8) + tid;          // 0..1023
      int m = f4 >> 4;                  // 0..63
      int kq = (f4 & 15) << 2;          // 0..60
      float4 av = *(const float4*)(A + (size_t)(bm + m) * 512 + k0 + kq);
      As[kq + 0][m] = av.x; As[kq + 1][m] = av.y; As[kq + 2][m] = av.z; As[kq + 3][m] = av.w;
      float4 bv = *(const float4*)(B + (size_t)(bn + m) * 512 + k0 + kq);
      Bs[kq + 0][m] = bv.x; Bs[kq + 1][m] = bv.y; Bs[kq + 2][m] = bv.z; Bs[kq + 3][m] = bv.w;
    }
    __syncthreads();
#pragma unroll
    for (int k = 0; k < 64; ++k) {
      float4 a4 = *(const float4*)(&As[k][ty << 2]);
      float4 b4 = *(const float4*)(&Bs[k][tx << 2]);
      float ar[4] = {a4.x, a4.y, a4.z, a4.w};
      float br[4] = {b4.x, b4.y, b4.z, b4.w};
#pragma unroll
      for (int i = 0; i < 4; ++i)
#pragma unroll
        for (int j = 0; j < 4; ++j) acc[i][j] = fmaf(ar[i], br[j], acc[i][j]);
    }
    __syncthreads();
  }
  const int n0 = bn + (tx << 2);
  float4 bsv = *(const float4*)(bias + n0);
#pragma unroll
  for (int i = 0; i < 4; ++i) {
    int m = bm + (ty << 2) + i;
    float4 res;
    res.x = acc[i][0] + bsv.x; res.y = acc[i][1] + bsv.y;
    res.z = acc[i][2] + bsv.z; res.w = acc[i][3] + bsv.w;
    if (add) {
      float4 ad = *(const float4*)(add + (size_t)m * N + n0);
      res.x += ad.x; res.y += ad.y; res.z += ad.z; res.w += ad.w;
    }
    *(float4*)(C + (size_t)m * N + n0) = res;
  }
}

// ---------- fused 2-layer persistent GRU scan v7: elected single-XCD L2 sync ----------
// 256 blocks x 1024 thr x ~152KB LDS -> 1 block/CU, all resident (pigeonhole).
// Deadlock-proof election: every block FIRST publishes its XCC to ctl[bid]
// (no waiting before publish). Block 0 (leader) waits for 256 publishes (or
// >=32 + realtime timeout), picks the MODAL XCC (>=32 blocks share it when IDs
// are real: exactly 32/XCD structurally), writes role table ctl[256+i] and a
// decision flag ctl[512]. All blocks poll only the flag, read their role, and
// exit if none. Every wait is on data guaranteed to arrive.
// Sync: tagged {value,tag} pairs (protocol of passing r8/r9). Producers DUAL-
// STORE each pair: sc0 (shared-L2 fast path) + agent scope (MALL truth); same
// value so ordering is irrelevant. Consumers poll sc0; a wave that spins 30K
// sweeps (mis-grouped XCC -> stale L2 line) stickily falls back to agent-scope
// polls, which the MALL copy satisfies. Wrong grouping degrades speed only.
__global__ __launch_bounds__(1024, 1) void k_gru_fused(
    const float* __restrict__ ih0,   // [T][1536] precomputed x@W_ih0^T + b_ih0
    const float* __restrict__ Whh0, const float* __restrict__ bhh0,
    const float* __restrict__ Wih1, const float* __restrict__ bih1,
    const float* __restrict__ Whh1, const float* __restrict__ bhh1,
    float* __restrict__ h1seq,       // [T][512]
    ull* __restrict__ ring0,         // [2][512] pairs, zeroed each launch
    ull* __restrict__ ring1,         // [2][512] pairs, zeroed each launch
    int* __restrict__ ctl) {         // [768] zeroed: publish|roles|flag
  __shared__ ushort wl[16][9][512];   // 147456B bf16 weights [row][gate][k]
  __shared__ float hb[2][1024];       // 8KB
  __shared__ int role_s;
  const int tid = threadIdx.x, bid = blockIdx.x;

  if (tid == 0) {
    // 1) publish unconditionally
    const int xcc = get_xcc_id();
    __hip_atomic_store(ctl + bid, 0x100 | xcc, __ATOMIC_RELAXED, __HIP_MEMORY_SCOPE_AGENT);
    // 2) leader elects
    if (bid == 0) {
      int xc[NLAUNCH];
      const long long t0 = __builtin_amdgcn_s_memrealtime();
      for (;;) {
        int C = 0;
        for (int i = 0; i < NLAUNCH; ++i) {
          xc[i] = __hip_atomic_load(ctl + i, __ATOMIC_RELAXED, __HIP_MEMORY_SCOPE_AGENT);
          if (xc[i]) ++C;
        }
        if (C == NLAUNCH) break;
        if (C >= NSCAN &&
            (__builtin_amdgcn_s_memrealtime() - t0) > 8000000LL) break;
        __builtin_amdgcn_s_sleep(4);
      }
      int cnt[16] = {};
      for (int i = 0; i < NLAUNCH; ++i) if (xc[i]) cnt[xc[i] & 15]++;
      int best = 0;
      for (int v = 1; v < 16; ++v) if (cnt[v] > cnt[best]) best = v;
      int role = 0;
      for (int pass = 0; pass < 2; ++pass)
        for (int i = 0; i < NLAUNCH && role < NSCAN; ++i) {
          if (!xc[i]) continue;
          const bool inModal = ((xc[i] & 15) == best);
          if ((pass == 0) != inModal) continue;
          __hip_atomic_store(ctl + 256 + i, role + 1, __ATOMIC_RELAXED, __HIP_MEMORY_SCOPE_AGENT);
          ++role;
        }
      __hip_atomic_store(ctl + 512, 1, __ATOMIC_RELAXED, __HIP_MEMORY_SCOPE_AGENT);
    }
    // 3) everyone: await decision, read my role
    while (__hip_atomic_load(ctl + 512, __ATOMIC_RELAXED, __HIP_MEMORY_SCOPE_AGENT) == 0)
      __builtin_amdgcn_s_sleep(8);
    role_s = __hip_atomic_load(ctl + 256 + bid, __ATOMIC_RELAXED, __HIP_MEMORY_SCOPE_AGENT) - 1;
  }
  __syncthreads();
  const int wg = role_s;
  if (wg < 0) return;                 // not a scan participant

  const int w = tid >> 6, l = tid & 63;
  const int base = wg << 4;
  const int r = base + w;             // this wave's row (0..511)

  // ---- stage weights to LDS as bf16 (once); gi: 0-2 Whh0, 3-5 Wih1, 6-8 Whh1
  for (int idx = tid; idx < 16 * 9 * 512; idx += 1024) {
    const int k = idx & 511;
    const int rest = idx >> 9;        // 0..143
    const int gi = rest % 9;
    const int rr = rest / 9;
    const int m = gi / 3, g = gi - m * 3;
    const float* srcm = (m == 0) ? Whh0 : ((m == 1) ? Wih1 : Whh1);
    const float v = srcm[((size_t)g << 18) + ((size_t)(base + rr) << 9) + k];
    unsigned u = __float_as_uint(v);
    u += 0x7FFFu + ((u >> 16) & 1u);  // RNE
    wl[rr][gi][k] = (ushort)(u >> 16);
  }
  float b9[9] = {};
  if (l == 0) {
#pragma unroll
    for (int g = 0; g < 3; ++g) {
      b9[g] = bhh0[(g << 9) + r];
      b9[3 + g] = bih1[(g << 9) + r];
      b9[6 + g] = bhh1[(g << 9) + r];
    }
  }
  __syncthreads();

  float h0own = 0.f, h1own = 0.f;     // lane 0 of each wave only
  const bool isH1 = (tid >= 512);
  const int pidx = tid & 511;         // my single poll pair
  bool fbk = false;                   // sticky agent-scope fallback (per wave)

  for (int t = 0; t <= T_STEPS; ++t) {
    // ih0 prefetch (independent of ring data; in flight during the poll)
    float i0 = 0.f, i1 = 0.f, i2 = 0.f;
    if (l == 0 && t < T_STEPS) {
      const float* p = ih0 + (size_t)t * 1536 + r;
      i0 = p[0]; i1 = p[512]; i2 = p[1024];
    }
    // ---- poll exactly ONE pair: sc0 (shared L2) with sticky MALL fallback ----
    {
      ull* sp = isH1 ? (ring1 + ((t & 1) << 9)) : (ring0 + (((t + 1) & 1) << 9));
      const unsigned expm = isH1 ? (unsigned)((t > 0) ? t - 1 : 0) : (unsigned)t;
      ull P;
      int sw = 0;
      for (;;) {
        P = fbk ? __hip_atomic_load(sp + pidx, __ATOMIC_RELAXED, __HIP_MEMORY_SCOPE_AGENT)
                : load_l2(sp + pidx);
        if (__ballot(((unsigned)P) != expm) == 0ull) break;
        if (++sw == 30000) fbk = true;
        if (sw > 4) __builtin_amdgcn_s_sleep(1);
      }
      hb[t & 1][tid] = __uint_as_float((unsigned)(P >> 32));
    }
    __syncthreads();   // single barrier per tick (hb double-buffered)
    // ---- h slices from LDS ----
    const float* hp = hb[t & 1];
    float4 h0a = *(const float4*)(hp + (l << 3));
    float4 h0b = *(const float4*)(hp + (l << 3) + 4);
    float4 h1a = *(const float4*)(hp + 512 + (l << 3));
    float4 h1b = *(const float4*)(hp + 512 + (l << 3) + 4);
    // ---- 9 gate dots (bf16 weights, contiguous b128 LDS reads) ----
    float acc[9];
#pragma unroll
    for (int gi = 0; gi < 9; ++gi) {
      const uint4 wv = *(const uint4*)(&wl[w][gi][l << 3]);
      const float4 ha = (gi < 6) ? h0a : h1a;
      const float4 hc = (gi < 6) ? h0b : h1b;
      float d = bf_lo(wv.x) * ha.x;
      d = fmaf(bf_hi(wv.x), ha.y, d);
      d = fmaf(bf_lo(wv.y), ha.z, d);
      d = fmaf(bf_hi(wv.y), ha.w, d);
      d = fmaf(bf_lo(wv.z), hc.x, d);
      d = fmaf(bf_hi(wv.z), hc.y, d);
      d = fmaf(bf_lo(wv.w), hc.z, d);
      d = fmaf(bf_hi(wv.w), hc.w, d);
      acc[gi] = d;
    }
#pragma unroll
    for (int m = 1; m < 64; m <<= 1)
#pragma unroll
      for (int i = 0; i < 9; ++i) acc[i] += __shfl_xor(acc[i], m);
    // ---- lane 0: activations, DUAL ring stores, output ----
    if (l == 0) {
      if (t < T_STEPS) {
        float rr = fast_sigmoid(i0 + acc[0] + b9[0]);
        float zz = fast_sigmoid(i1 + acc[1] + b9[1]);
        float nn = fast_tanh(fmaf(rr, acc[2] + b9[2], i2));
        h0own = fmaf(zz, h0own - nn, nn);
        ull pk = packpair(h0own, (unsigned)(t + 1));
        ull* dst = ring0 + ((t & 1) << 9) + r;
        store_l2(dst, pk);
        __hip_atomic_store(dst, pk, __ATOMIC_RELAXED, __HIP_MEMORY_SCOPE_AGENT);
      }
      if (t >= 1) {
        float rr = fast_sigmoid(acc[3] + b9[3] + acc[6] + b9[6]);
        float zz = fast_sigmoid(acc[4] + b9[4] + acc[7] + b9[7]);
        float nn = fast_tanh(fmaf(rr, acc[8] + b9[8], acc[5] + b9[5]));
        h1own = fmaf(zz, h1own - nn, nn);
        ull pk = packpair(h1own, (unsigned)t);
        ull* dst = ring1 + (((t + 1) & 1) << 9) + r;
        store_l2(dst, pk);
        __hip_atomic_store(dst, pk, __ATOMIC_RELAXED, __HIP_MEMORY_SCOPE_AGENT);
        h1seq[(size_t)(t - 1) * 512 + r] = h1own;
      }
    }
  }
}

// ---------- alpha = sigmoid(c . w + b), one wave per row ----------
__global__ __launch_bounds__(256) void k_alpha(const float* __restrict__ c,
                                               const float* __restrict__ w,
                                               const float* __restrict__ b,
                                               float* __restrict__ alpha) {
  const int wave = threadIdx.x >> 6, lane = threadIdx.x & 63;
  const int t = (blockIdx.x << 2) + wave;
  const float* cr = c + (size_t)t * 512;
  float acc = 0.f;
#pragma unroll
  for (int q = 0; q < 8; ++q) acc = fmaf(cr[lane + (q << 6)], w[lane + (q << 6)], acc);
#pragma unroll
  for (int m = 32; m; m >>= 1) acc += __shfl_xor(acc, m);
  if (lane == 0) alpha[t] = 1.f / (1.f + __expf(-(acc + b[0])));
}

// ---------- df_out grouped linear + tanh + conv(KT=2) add, one block per row ----------
__global__ __launch_bounds__(256) void k_dfout_conv(const float* __restrict__ c,
                                                    const float* __restrict__ Wd,
                                                    const float* __restrict__ c0,
                                                    const float* __restrict__ wc,
                                                    const float* __restrict__ bc,
                                                    float* __restrict__ out) {
  __shared__ float cs[512];
  __shared__ float A0[64 * 96];
  __shared__ float A1[64 * 96];
  __shared__ float wcs[1280];
  __shared__ float cc[960];
  const int t = blockIdx.x, tid = threadIdx.x;
  ((float2*)cs)[tid] = ((const float2*)(c + (size_t)t * 512))[tid];
  for (int idx = tid; idx < 64 * 96; idx += 256) {
    int ci = idx / 96, f = idx - ci * 96;
    size_t base = (size_t)ci * ((size_t)T_STEPS * 96) + (size_t)t * 96 + f;
    A1[idx] = c0[base];
    A0[idx] = (t == 0) ? 0.f : c0[base - 96];
  }
  for (int idx = tid; idx < 1280; idx += 256) wcs[idx] = wc[idx];
  __syncthreads();
  for (int idx = tid; idx < 960; idx += 256) {
    int f = idx / 10, co = idx - f * 10;
    float acc = bc[co];
    const float* w = wcs + (co << 7);  // (co, ci, kt)
#pragma unroll 16
    for (int ci = 0; ci < 64; ++ci) {
      acc = fmaf(A0[ci * 96 + f], w[ci * 2 + 0], acc);
      acc = fmaf(A1[ci * 96 + f], w[ci * 2 + 1], acc);
    }
    cc[idx] = acc;
  }
  __syncthreads();
  for (int idx = tid; idx < 960; idx += 256) {
    int g = idx / 120, o = idx - g * 120;
    const float* wp = Wd + g * 7680 + o;  // Wd[g][i][o], stride 120 over i
    const float* ep = cs + (g << 6);
    float acc = 0.f;
#pragma unroll 16
    for (int i = 0; i < 64; ++i) acc = fmaf(ep[i], wp[i * 120], acc);
    out[(size_t)t * 960 + idx] = tanhf(acc) + cc[idx];
  }
}

extern "C" void kernel_launch(void* const* d_in, const int* in_sizes, int n_in,
                              void* d_out, int out_size, void* d_ws, size_t ws_size,
                              hipStream_t stream) {
  const float* emb       = (const float*)d_in[0];
  const float* c0        = (const float*)d_in[1];
  const float* lin_in_w  = (const float*)d_in[2];
  const float* w_ih      = (const float*)d_in[3];  // (2,3,512,512)
  const float* w_hh      = (const float*)d_in[4];
  const float* b_ih      = (const float*)d_in[5];  // (2,3,512)
  const float* b_hh      = (const float*)d_in[6];
  const float* skip_w    = (const float*)d_in[7];
  const float* skip_b    = (const float*)d_in[8];
  const float* lin_out_w = (const float*)d_in[9];
  const float* df_skip_w = (const float*)d_in[10];
  const float* df_skip_b = (const float*)d_in[11];
  const float* fc_a_w    = (const float*)d_in[12];
  const float* fc_a_b    = (const float*)d_in[13];
  const float* df_out_w  = (const float*)d_in[14];
  const float* convp_w   = (const float*)d_in[15];
  const float* convp_b   = (const float*)d_in[16];

  const size_t T = T_STEPS;
  float* x    = (float*)d_ws;             // T*512
  float* ih   = x + T * 512;              // T*1536
  float* h1   = ih + T * 1536;            // T*512
  ull* ring0  = (ull*)(h1 + T * 512);     // 2*512 pairs
  ull* ring1  = ring0 + 1024;             // 2*512 pairs
  int* ctl    = (int*)(ring1 + 1024);     // 768 ints
  float* sbuf = ih;                       // reuse ih region after scan
  float* vbuf = ih + T * 512;
  float* cbuf = ih + 2 * T * 512;
  float* outc = (float*)d_out;
  float* outa = outc + T * 960;

  // x = relu(grouped_linear(emb, lin_in_w))
  k_grouped_relu<<<T_STEPS, 256, 0, stream>>>(emb, lin_in_w, x);
  // ih0 = x @ W_ih0^T + b_ih0
  k_gemm_rr<<<dim3(128, 24), 256, 0, stream>>>(x, w_ih, b_ih, nullptr, ih, 1536);
  // fused pipelined 2-layer scan (elected single-XCD L2 sync, MALL fallback)
  (void)hipMemsetAsync(ring0, 0, 2048 * sizeof(ull) + 768 * sizeof(int), stream);
  k_gru_fused<<<NLAUNCH, 1024, 0, stream>>>(ih, w_hh, b_hh,
                                            w_ih + 786432, b_ih + 1536,
                                            w_hh + 786432, b_hh + 1536,
                                            h1, ring0, ring1, ctl);
  // s = h1 + x @ skip_w^T + skip_b
  k_gemm_rr<<<dim3(128, 8), 256, 0, stream>>>(x, skip_w, skip_b, h1, sbuf, 512);
  // v = relu(grouped_linear(s, lin_out_w))
  k_grouped_relu<<<T_STEPS, 256, 0, stream>>>(sbuf, lin_out_w, vbuf);
  // c = v + emb @ df_skip_w^T + df_skip_b
  k_gemm_rr<<<dim3(128, 8), 256, 0, stream>>>(emb, df_skip_w, df_skip_b, vbuf, cbuf, 512);
  // alpha = sigmoid(c @ fc_a_w^T + fc_a_b)
  k_alpha<<<T_STEPS / 4, 256, 0, stream>>>(cbuf, fc_a_w, fc_a_b, outa);
  // out = tanh(grouped_linear(c, df_out_w)) + conv(c0)
  k_dfout_conv<<<T_STEPS, 256, 0, stream>>>(cbuf, df_out_w, c0, convp_w, convp_b, outc);
  (void)in_sizes; (void)n_in; (void)out_size; (void)ws_size;
}

// Round 12
// 32437.381 us; speedup vs baseline: 3.2865x; 3.2865x over previous
//
#include <hip/hip_runtime.h>
#include <hip/hip_bf16.h>
#include <cstdint>

#define T_STEPS 8192
#define NWG 64

typedef unsigned long long ull;

__device__ __forceinline__ float fast_sigmoid(float v) {
  return __fdividef(1.f, 1.f + __expf(-v));
}
__device__ __forceinline__ float fast_tanh(float v) {
  return 1.f - __fdividef(2.f, __expf(2.f * v) + 1.f);
}
__device__ __forceinline__ ull packpair(float v, unsigned tag) {
  return ((ull)__float_as_uint(v) << 32) | (ull)tag;
}
__device__ __forceinline__ float bf_lo(unsigned u) { return __uint_as_float(u << 16); }
__device__ __forceinline__ float bf_hi(unsigned u) { return __uint_as_float(u & 0xFFFF0000u); }

// ---------- grouped linear (8 groups of 64x64) + relu, one block per row ----------
__global__ __launch_bounds__(256) void k_grouped_relu(const float* __restrict__ in,
                                                      const float* __restrict__ W,
                                                      float* __restrict__ out) {
  __shared__ float es[512];
  const int t = blockIdx.x;
  const int tid = threadIdx.x;
  const float* inr = in + (size_t)t * 512;
  ((float2*)es)[tid] = ((const float2*)inr)[tid];
  __syncthreads();
#pragma unroll
  for (int rep = 0; rep < 2; ++rep) {
    int jj = tid + rep * 256;
    int g = jj >> 6, o = jj & 63;
    const float* wp = W + (g << 12) + o;   // W[g][i][o], stride 64 over i
    const float* ep = es + (g << 6);
    float acc = 0.f;
#pragma unroll 8
    for (int i = 0; i < 64; ++i) acc = fmaf(ep[i], wp[i << 6], acc);
    out[(size_t)t * 512 + jj] = fmaxf(acc, 0.f);
  }
}

// ---------- C[M,N] = A[M,512] * B[N,512]^T + bias[N] (+ add[M,N]) ----------
__global__ __launch_bounds__(256) void k_gemm_rr(const float* __restrict__ A,
                                                 const float* __restrict__ B,
                                                 const float* __restrict__ bias,
                                                 const float* __restrict__ add,
                                                 float* __restrict__ C, int N) {
  __shared__ float As[64][68];  // [k][m]
  __shared__ float Bs[64][68];  // [k][n]
  const int bm = blockIdx.x << 6, bn = blockIdx.y << 6;
  const int tid = threadIdx.x;
  const int tx = tid & 15, ty = tid >> 4;
  float acc[4][4] = {};
  for (int k0 = 0; k0 < 512; k0 += 64) {
#pragma unroll
    for (int u = 0; u < 4; ++u) {
      int f4 = (u << 8) + tid;          // 0..1023
      int m = f4 >> 4;                  // 0..63
      int kq = (f4 & 15) << 2;          // 0..60
      float4 av = *(const float4*)(A + (size_t)(bm + m) * 512 + k0 + kq);
      As[kq + 0][m] = av.x; As[kq + 1][m] = av.y; As[kq + 2][m] = av.z; As[kq + 3][m] = av.w;
      float4 bv = *(const float4*)(B + (size_t)(bn + m) * 512 + k0 + kq);
      Bs[kq + 0][m] = bv.x; Bs[kq + 1][m] = bv.y; Bs[kq + 2][m] = bv.z; Bs[kq + 3][m] = bv.w;
    }
    __syncthreads();
#pragma unroll
    for (int k = 0; k < 64; ++k) {
      float4 a4 = *(const float4*)(&As[k][ty << 2]);
      float4 b4 = *(const float4*)(&Bs[k][tx << 2]);
      float ar[4] = {a4.x, a4.y, a4.z, a4.w};
      float br[4] = {b4.x, b4.y, b4.z, b4.w};
#pragma unroll
      for (int i = 0; i < 4; ++i)
#pragma unroll
        for (int j = 0; j < 4; ++j) acc[i][j] = fmaf(ar[i], br[j], acc[i][j]);
    }
    __syncthreads();
  }
  const int n0 = bn + (tx << 2);
  float4 bsv = *(const float4*)(bias + n0);
#pragma unroll
  for (int i = 0; i < 4; ++i) {
    int m = bm + (ty << 2) + i;
    float4 res;
    res.x = acc[i][0] + bsv.x; res.y = acc[i][1] + bsv.y;
    res.z = acc[i][2] + bsv.z; res.w = acc[i][3] + bsv.w;
    if (add) {
      float4 ad = *(const float4*)(add + (size_t)m * N + n0);
      res.x += ad.x; res.y += ad.y; res.z += ad.z; res.w += ad.w;
    }
    *(float4*)(C + (size_t)m * N + n0) = res;
  }
}

// ---------- fused 2-layer persistent GRU scan v8 ----------
// r6 geometry (the fastest sync structure measured: 64 WGs x 512 thr, 3.8us/
// tick) + bf16 weights in LDS (r6's VGPR=68 proved its weights re-streamed
// from L2 every tick, ~1.1us on the critical path; LDS residency is
// structural). Wave w owns row r = wg*8+w of BOTH layers.
// LDS: wl[8][9][512] bf16 = 73.7KB + hb[2][1024] = 8KB.
// Sync (r6/r8/r9-proven): tagged {value,tag} pairs, relaxed agent atomics,
// tight no-sleep polls. Waves 0-3 poll h0's 512 pairs (2/thread), waves 4-7
// poll h1's; deposits into double-buffered hb[t&1]; ONE barrier per tick
// (r7 argument: a thread passing barrier(t+1) proves all threads finished
// tick-t LDS reads, so t+2 deposits into hb[t&1] cannot race).
// Tick t: needs h0[t-1] (ring0 slot (t+1)&1, tag t) and h1[t-2] (ring1 slot
// t&1, tag max(t-1,0)); stores h0[t] (slot t&1, tag t+1), h1[t-1] (slot
// (t+1)&1, tag t). Rings memset 0 each launch = valid t=0 state. Slot reuse
// transitively safe (store is control-dependent on completed polls).
__global__ __launch_bounds__(512, 1) void k_gru_fused(
    const float* __restrict__ ih0,   // [T][1536] precomputed x@W_ih0^T + b_ih0
    const float* __restrict__ Whh0, const float* __restrict__ bhh0,
    const float* __restrict__ Wih1, const float* __restrict__ bih1,
    const float* __restrict__ Whh1, const float* __restrict__ bhh1,
    float* __restrict__ h1seq,       // [T][512]
    ull* __restrict__ ring0,         // [2][512] pairs, zeroed each launch
    ull* __restrict__ ring1) {       // [2][512] pairs, zeroed each launch
  __shared__ ushort wl[8][9][512];    // 73728B bf16 weights [row][gate][k]
  __shared__ float hb[2][1024];       // 8KB: [buf][0..511]=h0, [512..1023]=h1
  const int wg = blockIdx.x, tid = threadIdx.x;
  const int w = tid >> 6, l = tid & 63;
  const int base = wg << 3;
  const int r = base + w;             // this wave's row (0..511)

  // ---- stage weights to LDS as bf16 (once); gi: 0-2 Whh0, 3-5 Wih1, 6-8 Whh1
  for (int idx = tid; idx < 8 * 9 * 512; idx += 512) {
    const int k = idx & 511;
    const int rest = idx >> 9;        // 0..71
    const int gi = rest % 9;
    const int rr = rest / 9;
    const int m = gi / 3, g = gi - m * 3;
    const float* srcm = (m == 0) ? Whh0 : ((m == 1) ? Wih1 : Whh1);
    const float v = srcm[((size_t)g << 18) + ((size_t)(base + rr) << 9) + k];
    unsigned u = __float_as_uint(v);
    u += 0x7FFFu + ((u >> 16) & 1u);  // RNE
    wl[rr][gi][k] = (ushort)(u >> 16);
  }
  float b9[9] = {};
  if (l == 0) {
#pragma unroll
    for (int g = 0; g < 3; ++g) {
      b9[g] = bhh0[(g << 9) + r];
      b9[3 + g] = bih1[(g << 9) + r];
      b9[6 + g] = bhh1[(g << 9) + r];
    }
  }
  __syncthreads();

  float h0own = 0.f, h1own = 0.f;     // lane 0 of each wave only
  const bool isH1 = (w >= 4);         // waves 4-7 poll ring1
  const int pidx = ((w & 3) << 6) + l;  // 0..255; polls pairs pidx, pidx+256
  const int doff = isH1 ? 512 : 0;

  for (int t = 0; t <= T_STEPS; ++t) {
    // ih0 prefetch (independent of ring data; in flight during the poll)
    float i0 = 0.f, i1 = 0.f, i2 = 0.f;
    if (l == 0 && t < T_STEPS) {
      const float* p = ih0 + (size_t)t * 1536 + r;
      i0 = p[0]; i1 = p[512]; i2 = p[1024];
    }
    // ---- poll my 2 pairs (tight, r6-style), deposit into hb[t&1] ----
    {
      ull* sp = isH1 ? (ring1 + ((t & 1) << 9)) : (ring0 + (((t + 1) & 1) << 9));
      const unsigned expm = isH1 ? (unsigned)((t > 0) ? t - 1 : 0) : (unsigned)t;
      ull Pa, Pb;
      for (;;) {
        Pa = __hip_atomic_load(sp + pidx, __ATOMIC_RELAXED, __HIP_MEMORY_SCOPE_AGENT);
        Pb = __hip_atomic_load(sp + pidx + 256, __ATOMIC_RELAXED, __HIP_MEMORY_SCOPE_AGENT);
        bool bad = (((unsigned)Pa) != expm) | (((unsigned)Pb) != expm);
        if (__ballot(bad) == 0ull) break;
      }
      float* dst = hb[t & 1] + doff;
      dst[pidx] = __uint_as_float((unsigned)(Pa >> 32));
      dst[pidx + 256] = __uint_as_float((unsigned)(Pb >> 32));
    }
    __syncthreads();   // single barrier per tick (hb double-buffered)
    // ---- h slices from LDS ----
    const float* hp = hb[t & 1];
    float4 h0a = *(const float4*)(hp + (l << 3));
    float4 h0b = *(const float4*)(hp + (l << 3) + 4);
    float4 h1a = *(const float4*)(hp + 512 + (l << 3));
    float4 h1b = *(const float4*)(hp + 512 + (l << 3) + 4);
    // ---- 9 gate dots (bf16 LDS weights, contiguous b128 reads) ----
    float acc[9];
#pragma unroll
    for (int gi = 0; gi < 9; ++gi) {
      const uint4 wv = *(const uint4*)(&wl[w][gi][l << 3]);
      const float4 ha = (gi < 6) ? h0a : h1a;
      const float4 hc = (gi < 6) ? h0b : h1b;
      float d = bf_lo(wv.x) * ha.x;
      d = fmaf(bf_hi(wv.x), ha.y, d);
      d = fmaf(bf_lo(wv.y), ha.z, d);
      d = fmaf(bf_hi(wv.y), ha.w, d);
      d = fmaf(bf_lo(wv.z), hc.x, d);
      d = fmaf(bf_hi(wv.z), hc.y, d);
      d = fmaf(bf_lo(wv.w), hc.z, d);
      d = fmaf(bf_hi(wv.w), hc.w, d);
      acc[gi] = d;
    }
#pragma unroll
    for (int m = 1; m < 64; m <<= 1)
#pragma unroll
      for (int i = 0; i < 9; ++i) acc[i] += __shfl_xor(acc[i], m);
    // ---- lane 0: activations, ring stores, output ----
    if (l == 0) {
      if (t < T_STEPS) {
        float rr = fast_sigmoid(i0 + acc[0] + b9[0]);
        float zz = fast_sigmoid(i1 + acc[1] + b9[1]);
        float nn = fast_tanh(fmaf(rr, acc[2] + b9[2], i2));
        h0own = fmaf(zz, h0own - nn, nn);
        __hip_atomic_store(ring0 + ((t & 1) << 9) + r, packpair(h0own, (unsigned)(t + 1)),
                           __ATOMIC_RELAXED, __HIP_MEMORY_SCOPE_AGENT);
      }
      if (t >= 1) {
        float rr = fast_sigmoid(acc[3] + b9[3] + acc[6] + b9[6]);
        float zz = fast_sigmoid(acc[4] + b9[4] + acc[7] + b9[7]);
        float nn = fast_tanh(fmaf(rr, acc[8] + b9[8], acc[5] + b9[5]));
        h1own = fmaf(zz, h1own - nn, nn);
        __hip_atomic_store(ring1 + (((t + 1) & 1) << 9) + r, packpair(h1own, (unsigned)t),
                           __ATOMIC_RELAXED, __HIP_MEMORY_SCOPE_AGENT);
        h1seq[(size_t)(t - 1) * 512 + r] = h1own;
      }
    }
  }
}

// ---------- alpha = sigmoid(c . w + b), one wave per row ----------
__global__ __launch_bounds__(256) void k_alpha(const float* __restrict__ c,
                                               const float* __restrict__ w,
                                               const float* __restrict__ b,
                                               float* __restrict__ alpha) {
  const int wave = threadIdx.x >> 6, lane = threadIdx.x & 63;
  const int t = (blockIdx.x << 2) + wave;
  const float* cr = c + (size_t)t * 512;
  float acc = 0.f;
#pragma unroll
  for (int q = 0; q < 8; ++q) acc = fmaf(cr[lane + (q << 6)], w[lane + (q << 6)], acc);
#pragma unroll
  for (int m = 32; m; m >>= 1) acc += __shfl_xor(acc, m);
  if (lane == 0) alpha[t] = 1.f / (1.f + __expf(-(acc + b[0])));
}

// ---------- df_out grouped linear + tanh + conv(KT=2) add, one block per row ----------
__global__ __launch_bounds__(256) void k_dfout_conv(const float* __restrict__ c,
                                                    const float* __restrict__ Wd,
                                                    const float* __restrict__ c0,
                                                    const float* __restrict__ wc,
                                                    const float* __restrict__ bc,
                                                    float* __restrict__ out) {
  __shared__ float cs[512];
  __shared__ float A0[64 * 96];
  __shared__ float A1[64 * 96];
  __shared__ float wcs[1280];
  __shared__ float cc[960];
  const int t = blockIdx.x, tid = threadIdx.x;
  ((float2*)cs)[tid] = ((const float2*)(c + (size_t)t * 512))[tid];
  for (int idx = tid; idx < 64 * 96; idx += 256) {
    int ci = idx / 96, f = idx - ci * 96;
    size_t base = (size_t)ci * ((size_t)T_STEPS * 96) + (size_t)t * 96 + f;
    A1[idx] = c0[base];
    A0[idx] = (t == 0) ? 0.f : c0[base - 96];
  }
  for (int idx = tid; idx < 1280; idx += 256) wcs[idx] = wc[idx];
  __syncthreads();
  for (int idx = tid; idx < 960; idx += 256) {
    int f = idx / 10, co = idx - f * 10;
    float acc = bc[co];
    const float* w = wcs + (co << 7);  // (co, ci, kt)
#pragma unroll 16
    for (int ci = 0; ci < 64; ++ci) {
      acc = fmaf(A0[ci * 96 + f], w[ci * 2 + 0], acc);
      acc = fmaf(A1[ci * 96 + f], w[ci * 2 + 1], acc);
    }
    cc[idx] = acc;
  }
  __syncthreads();
  for (int idx = tid; idx < 960; idx += 256) {
    int g = idx / 120, o = idx - g * 120;
    const float* wp = Wd + g * 7680 + o;  // Wd[g][i][o], stride 120 over i
    const float* ep = cs + (g << 6);
    float acc = 0.f;
#pragma unroll 16
    for (int i = 0; i < 64; ++i) acc = fmaf(ep[i], wp[i * 120], acc);
    out[(size_t)t * 960 + idx] = tanhf(acc) + cc[idx];
  }
}

extern "C" void kernel_launch(void* const* d_in, const int* in_sizes, int n_in,
                              void* d_out, int out_size, void* d_ws, size_t ws_size,
                              hipStream_t stream) {
  const float* emb       = (const float*)d_in[0];
  const float* c0        = (const float*)d_in[1];
  const float* lin_in_w  = (const float*)d_in[2];
  const float* w_ih      = (const float*)d_in[3];  // (2,3,512,512)
  const float* w_hh      = (const float*)d_in[4];
  const float* b_ih      = (const float*)d_in[5];  // (2,3,512)
  const float* b_hh      = (const float*)d_in[6];
  const float* skip_w    = (const float*)d_in[7];
  const float* skip_b    = (const float*)d_in[8];
  const float* lin_out_w = (const float*)d_in[9];
  const float* df_skip_w = (const float*)d_in[10];
  const float* df_skip_b = (const float*)d_in[11];
  const float* fc_a_w    = (const float*)d_in[12];
  const float* fc_a_b    = (const float*)d_in[13];
  const float* df_out_w  = (const float*)d_in[14];
  const float* convp_w   = (const float*)d_in[15];
  const float* convp_b   = (const float*)d_in[16];

  const size_t T = T_STEPS;
  float* x    = (float*)d_ws;             // T*512
  float* ih   = x + T * 512;              // T*1536
  float* h1   = ih + T * 1536;            // T*512
  ull* ring0  = (ull*)(h1 + T * 512);     // 2*512 pairs
  ull* ring1  = ring0 + 1024;             // 2*512 pairs
  float* sbuf = ih;                       // reuse ih region after scan
  float* vbuf = ih + T * 512;
  float* cbuf = ih + 2 * T * 512;
  float* outc = (float*)d_out;
  float* outa = outc + T * 960;

  // x = relu(grouped_linear(emb, lin_in_w))
  k_grouped_relu<<<T_STEPS, 256, 0, stream>>>(emb, lin_in_w, x);
  // ih0 = x @ W_ih0^T + b_ih0
  k_gemm_rr<<<dim3(128, 24), 256, 0, stream>>>(x, w_ih, b_ih, nullptr, ih, 1536);
  // fused pipelined 2-layer scan (r6 sync geometry + bf16 LDS weights)
  (void)hipMemsetAsync(ring0, 0, 2048 * sizeof(ull), stream);
  k_gru_fused<<<NWG, 512, 0, stream>>>(ih, w_hh, b_hh,
                                       w_ih + 786432, b_ih + 1536,
                                       w_hh + 786432, b_hh + 1536,
                                       h1, ring0, ring1);
  // s = h1 + x @ skip_w^T + skip_b
  k_gemm_rr<<<dim3(128, 8), 256, 0, stream>>>(x, skip_w, skip_b, h1, sbuf, 512);
  // v = relu(grouped_linear(s, lin_out_w))
  k_grouped_relu<<<T_STEPS, 256, 0, stream>>>(sbuf, lin_out_w, vbuf);
  // c = v + emb @ df_skip_w^T + df_skip_b
  k_gemm_rr<<<dim3(128, 8), 256, 0, stream>>>(emb, df_skip_w, df_skip_b, vbuf, cbuf, 512);
  // alpha = sigmoid(c @ fc_a_w^T + fc_a_b)
  k_alpha<<<T_STEPS / 4, 256, 0, stream>>>(cbuf, fc_a_w, fc_a_b, outa);
  // out = tanh(grouped_linear(c, df_out_w)) + conv(c0)
  k_dfout_conv<<<T_STEPS, 256, 0, stream>>>(cbuf, df_out_w, c0, convp_w, convp_b, outc);
  (void)in_sizes; (void)n_in; (void)out_size; (void)ws_size;
}

// Round 13
// 32167.932 us; speedup vs baseline: 3.3140x; 1.0084x over previous
//
#include <hip/hip_runtime.h>
#include <hip/hip_bf16.h>
#include <cstdint>

#define T_STEPS 8192
#define NWG 64

typedef unsigned long long ull;

__device__ __forceinline__ float fast_sigmoid(float v) {
  return __fdividef(1.f, 1.f + __expf(-v));
}
__device__ __forceinline__ float fast_tanh(float v) {
  return 1.f - __fdividef(2.f, __expf(2.f * v) + 1.f);
}
__device__ __forceinline__ ull packpair(float v, unsigned tag) {
  return ((ull)__float_as_uint(v) << 32) | (ull)tag;
}
__device__ __forceinline__ float bf_lo(unsigned u) { return __uint_as_float(u << 16); }
__device__ __forceinline__ float bf_hi(unsigned u) { return __uint_as_float(u & 0xFFFF0000u); }

// ---------- grouped linear (8 groups of 64x64) + relu, one block per row ----------
__global__ __launch_bounds__(256) void k_grouped_relu(const float* __restrict__ in,
                                                      const float* __restrict__ W,
                                                      float* __restrict__ out) {
  __shared__ float es[512];
  const int t = blockIdx.x;
  const int tid = threadIdx.x;
  const float* inr = in + (size_t)t * 512;
  ((float2*)es)[tid] = ((const float2*)inr)[tid];
  __syncthreads();
#pragma unroll
  for (int rep = 0; rep < 2; ++rep) {
    int jj = tid + rep * 256;
    int g = jj >> 6, o = jj & 63;
    const float* wp = W + (g << 12) + o;   // W[g][i][o], stride 64 over i
    const float* ep = es + (g << 6);
    float acc = 0.f;
#pragma unroll 8
    for (int i = 0; i < 64; ++i) acc = fmaf(ep[i], wp[i << 6], acc);
    out[(size_t)t * 512 + jj] = fmaxf(acc, 0.f);
  }
}

// ---------- C[M,N] = A[M,512] * B[N,512]^T + bias[N] (+ add[M,N]) ----------
__global__ __launch_bounds__(256) void k_gemm_rr(const float* __restrict__ A,
                                                 const float* __restrict__ B,
                                                 const float* __restrict__ bias,
                                                 const float* __restrict__ add,
                                                 float* __restrict__ C, int N) {
  __shared__ float As[64][68];  // [k][m]
  __shared__ float Bs[64][68];  // [k][n]
  const int bm = blockIdx.x << 6, bn = blockIdx.y << 6;
  const int tid = threadIdx.x;
  const int tx = tid & 15, ty = tid >> 4;
  float acc[4][4] = {};
  for (int k0 = 0; k0 < 512; k0 += 64) {
#pragma unroll
    for (int u = 0; u < 4; ++u) {
      int f4 = (u << 8) + tid;          // 0..1023
      int m = f4 >> 4;                  // 0..63
      int kq = (f4 & 15) << 2;          // 0..60
      float4 av = *(const float4*)(A + (size_t)(bm + m) * 512 + k0 + kq);
      As[kq + 0][m] = av.x; As[kq + 1][m] = av.y; As[kq + 2][m] = av.z; As[kq + 3][m] = av.w;
      float4 bv = *(const float4*)(B + (size_t)(bn + m) * 512 + k0 + kq);
      Bs[kq + 0][m] = bv.x; Bs[kq + 1][m] = bv.y; Bs[kq + 2][m] = bv.z; Bs[kq + 3][m] = bv.w;
    }
    __syncthreads();
#pragma unroll
    for (int k = 0; k < 64; ++k) {
      float4 a4 = *(const float4*)(&As[k][ty << 2]);
      float4 b4 = *(const float4*)(&Bs[k][tx << 2]);
      float ar[4] = {a4.x, a4.y, a4.z, a4.w};
      float br[4] = {b4.x, b4.y, b4.z, b4.w};
#pragma unroll
      for (int i = 0; i < 4; ++i)
#pragma unroll
        for (int j = 0; j < 4; ++j) acc[i][j] = fmaf(ar[i], br[j], acc[i][j]);
    }
    __syncthreads();
  }
  const int n0 = bn + (tx << 2);
  float4 bsv = *(const float4*)(bias + n0);
#pragma unroll
  for (int i = 0; i < 4; ++i) {
    int m = bm + (ty << 2) + i;
    float4 res;
    res.x = acc[i][0] + bsv.x; res.y = acc[i][1] + bsv.y;
    res.z = acc[i][2] + bsv.z; res.w = acc[i][3] + bsv.w;
    if (add) {
      float4 ad = *(const float4*)(add + (size_t)m * N + n0);
      res.x += ad.x; res.y += ad.y; res.z += ad.z; res.w += ad.w;
    }
    *(float4*)(C + (size_t)m * N + n0) = res;
  }
}

// ---------- fused 2-layer persistent GRU scan v9 ----------
// r12 base (64 WGs x 512 thr, bf16 LDS weights, tagged-pair dataflow) with the
// serial chain shortened:
//  (1) layer-0-first: only the 3 layer-0 gate dots + their reduce sit between
//      poll-complete and the h0 ring store (sched_barrier pins the order);
//      layer-1's 6 dots/reduce/store run after the critical store.
//  (2) adjacent-pair polls: poller q handles pairs {2q,2q+1} (one 16B chunk,
//      one cache line) instead of {q,q+256} (2KB apart) -> 4 lines/wave/sweep
//      instead of 16.
// Protocol identical to r8/r9/r12 (passing): tick t needs h0[t-1] (ring0 slot
// (t+1)&1, tag t) and h1[t-2] (ring1 slot t&1, tag max(t-1,0)); stores h0[t]
// (slot t&1, tag t+1), h1[t-1] (slot (t+1)&1, tag t). Rings memset 0 = valid
// t=0 state. Slot-reuse transitively safe: the ring store follows the WG's
// barrier, hence all its threads' polls/reads of the slot being overwritten.
__global__ __launch_bounds__(512, 1) void k_gru_fused(
    const float* __restrict__ ih0,   // [T][1536] precomputed x@W_ih0^T + b_ih0
    const float* __restrict__ Whh0, const float* __restrict__ bhh0,
    const float* __restrict__ Wih1, const float* __restrict__ bih1,
    const float* __restrict__ Whh1, const float* __restrict__ bhh1,
    float* __restrict__ h1seq,       // [T][512]
    ull* __restrict__ ring0,         // [2][512] pairs, zeroed each launch
    ull* __restrict__ ring1) {       // [2][512] pairs, zeroed each launch
  __shared__ ushort wl[8][9][512];    // 73728B bf16 weights [row][gate][k]
  __shared__ float hb[2][1024];       // 8KB: [buf][0..511]=h0, [512..1023]=h1
  const int wg = blockIdx.x, tid = threadIdx.x;
  const int w = tid >> 6, l = tid & 63;
  const int base = wg << 3;
  const int r = base + w;             // this wave's row (0..511)

  // ---- stage weights to LDS as bf16 (once); gi: 0-2 Whh0, 3-5 Wih1, 6-8 Whh1
  for (int idx = tid; idx < 8 * 9 * 512; idx += 512) {
    const int k = idx & 511;
    const int rest = idx >> 9;        // 0..71
    const int gi = rest % 9;
    const int rr = rest / 9;
    const int m = gi / 3, g = gi - m * 3;
    const float* srcm = (m == 0) ? Whh0 : ((m == 1) ? Wih1 : Whh1);
    const float v = srcm[((size_t)g << 18) + ((size_t)(base + rr) << 9) + k];
    unsigned u = __float_as_uint(v);
    u += 0x7FFFu + ((u >> 16) & 1u);  // RNE
    wl[rr][gi][k] = (ushort)(u >> 16);
  }
  float b9[9] = {};
  if (l == 0) {
#pragma unroll
    for (int g = 0; g < 3; ++g) {
      b9[g] = bhh0[(g << 9) + r];
      b9[3 + g] = bih1[(g << 9) + r];
      b9[6 + g] = bhh1[(g << 9) + r];
    }
  }
  __syncthreads();

  float h0own = 0.f, h1own = 0.f;     // lane 0 of each wave only
  const bool isH1 = (tid >= 256);     // waves 4-7 poll ring1
  const int q = tid & 255;            // poller index; polls pairs 2q, 2q+1
  const int doff = isH1 ? 512 : 0;

  for (int t = 0; t <= T_STEPS; ++t) {
    // ih0 prefetch (independent of ring data; in flight during the poll)
    float i0 = 0.f, i1 = 0.f, i2 = 0.f;
    if (l == 0 && t < T_STEPS) {
      const float* p = ih0 + (size_t)t * 1536 + r;
      i0 = p[0]; i1 = p[512]; i2 = p[1024];
    }
    // ---- poll my 2 ADJACENT pairs (one cache line), deposit as float2 ----
    {
      ull* sp = isH1 ? (ring1 + ((t & 1) << 9)) : (ring0 + (((t + 1) & 1) << 9));
      const unsigned expm = isH1 ? (unsigned)((t > 0) ? t - 1 : 0) : (unsigned)t;
      ull Pa, Pb;
      for (;;) {
        Pa = __hip_atomic_load(sp + 2 * q, __ATOMIC_RELAXED, __HIP_MEMORY_SCOPE_AGENT);
        Pb = __hip_atomic_load(sp + 2 * q + 1, __ATOMIC_RELAXED, __HIP_MEMORY_SCOPE_AGENT);
        bool bad = (((unsigned)Pa) != expm) | (((unsigned)Pb) != expm);
        if (__ballot(bad) == 0ull) break;
      }
      float2 v;
      v.x = __uint_as_float((unsigned)(Pa >> 32));
      v.y = __uint_as_float((unsigned)(Pb >> 32));
      *(float2*)(hb[t & 1] + doff + 2 * q) = v;
    }
    __syncthreads();   // single barrier per tick (hb double-buffered)
    const float* hp = hb[t & 1];
    // ---- CRITICAL PATH: layer-0 gates only ----
    float4 h0a = *(const float4*)(hp + (l << 3));
    float4 h0b = *(const float4*)(hp + (l << 3) + 4);
    float a0, a1, a2;
    {
      float acc3[3];
#pragma unroll
      for (int gi = 0; gi < 3; ++gi) {
        const uint4 wv = *(const uint4*)(&wl[w][gi][l << 3]);
        float d = bf_lo(wv.x) * h0a.x;
        d = fmaf(bf_hi(wv.x), h0a.y, d);
        d = fmaf(bf_lo(wv.y), h0a.z, d);
        d = fmaf(bf_hi(wv.y), h0a.w, d);
        d = fmaf(bf_lo(wv.z), h0b.x, d);
        d = fmaf(bf_hi(wv.z), h0b.y, d);
        d = fmaf(bf_lo(wv.w), h0b.z, d);
        d = fmaf(bf_hi(wv.w), h0b.w, d);
        acc3[gi] = d;
      }
#pragma unroll
      for (int m = 1; m < 64; m <<= 1) {
        acc3[0] += __shfl_xor(acc3[0], m);
        acc3[1] += __shfl_xor(acc3[1], m);
        acc3[2] += __shfl_xor(acc3[2], m);
      }
      a0 = acc3[0]; a1 = acc3[1]; a2 = acc3[2];
    }
    if (l == 0 && t < T_STEPS) {
      float rr = fast_sigmoid(i0 + a0 + b9[0]);
      float zz = fast_sigmoid(i1 + a1 + b9[1]);
      float nn = fast_tanh(fmaf(rr, a2 + b9[2], i2));
      h0own = fmaf(zz, h0own - nn, nn);
      __hip_atomic_store(ring0 + ((t & 1) << 9) + r, packpair(h0own, (unsigned)(t + 1)),
                         __ATOMIC_RELAXED, __HIP_MEMORY_SCOPE_AGENT);
    }
    __builtin_amdgcn_sched_barrier(0);   // keep layer-1 work below the h0 store
    // ---- off-path: layer-1 gates ----
    float4 h1a = *(const float4*)(hp + 512 + (l << 3));
    float4 h1b = *(const float4*)(hp + 512 + (l << 3) + 4);
    float acc6[6];
#pragma unroll
    for (int gi = 0; gi < 6; ++gi) {
      const uint4 wv = *(const uint4*)(&wl[w][3 + gi][l << 3]);
      const float4 ha = (gi < 3) ? h0a : h1a;
      const float4 hc = (gi < 3) ? h0b : h1b;
      float d = bf_lo(wv.x) * ha.x;
      d = fmaf(bf_hi(wv.x), ha.y, d);
      d = fmaf(bf_lo(wv.y), ha.z, d);
      d = fmaf(bf_hi(wv.y), ha.w, d);
      d = fmaf(bf_lo(wv.z), hc.x, d);
      d = fmaf(bf_hi(wv.z), hc.y, d);
      d = fmaf(bf_lo(wv.w), hc.z, d);
      d = fmaf(bf_hi(wv.w), hc.w, d);
      acc6[gi] = d;
    }
#pragma unroll
    for (int m = 1; m < 64; m <<= 1)
#pragma unroll
      for (int i = 0; i < 6; ++i) acc6[i] += __shfl_xor(acc6[i], m);
    if (l == 0 && t >= 1) {
      float rr = fast_sigmoid(acc6[0] + b9[3] + acc6[3] + b9[6]);
      float zz = fast_sigmoid(acc6[1] + b9[4] + acc6[4] + b9[7]);
      float nn = fast_tanh(fmaf(rr, acc6[5] + b9[8], acc6[2] + b9[5]));
      h1own = fmaf(zz, h1own - nn, nn);
      __hip_atomic_store(ring1 + (((t + 1) & 1) << 9) + r, packpair(h1own, (unsigned)t),
                         __ATOMIC_RELAXED, __HIP_MEMORY_SCOPE_AGENT);
      h1seq[(size_t)(t - 1) * 512 + r] = h1own;
    }
  }
}

// ---------- alpha = sigmoid(c . w + b), one wave per row ----------
__global__ __launch_bounds__(256) void k_alpha(const float* __restrict__ c,
                                               const float* __restrict__ w,
                                               const float* __restrict__ b,
                                               float* __restrict__ alpha) {
  const int wave = threadIdx.x >> 6, lane = threadIdx.x & 63;
  const int t = (blockIdx.x << 2) + wave;
  const float* cr = c + (size_t)t * 512;
  float acc = 0.f;
#pragma unroll
  for (int q = 0; q < 8; ++q) acc = fmaf(cr[lane + (q << 6)], w[lane + (q << 6)], acc);
#pragma unroll
  for (int m = 32; m; m >>= 1) acc += __shfl_xor(acc, m);
  if (lane == 0) alpha[t] = 1.f / (1.f + __expf(-(acc + b[0])));
}

// ---------- df_out grouped linear + tanh + conv(KT=2) add, one block per row ----------
__global__ __launch_bounds__(256) void k_dfout_conv(const float* __restrict__ c,
                                                    const float* __restrict__ Wd,
                                                    const float* __restrict__ c0,
                                                    const float* __restrict__ wc,
                                                    const float* __restrict__ bc,
                                                    float* __restrict__ out) {
  __shared__ float cs[512];
  __shared__ float A0[64 * 96];
  __shared__ float A1[64 * 96];
  __shared__ float wcs[1280];
  __shared__ float cc[960];
  const int t = blockIdx.x, tid = threadIdx.x;
  ((float2*)cs)[tid] = ((const float2*)(c + (size_t)t * 512))[tid];
  for (int idx = tid; idx < 64 * 96; idx += 256) {
    int ci = idx / 96, f = idx - ci * 96;
    size_t base = (size_t)ci * ((size_t)T_STEPS * 96) + (size_t)t * 96 + f;
    A1[idx] = c0[base];
    A0[idx] = (t == 0) ? 0.f : c0[base - 96];
  }
  for (int idx = tid; idx < 1280; idx += 256) wcs[idx] = wc[idx];
  __syncthreads();
  for (int idx = tid; idx < 960; idx += 256) {
    int f = idx / 10, co = idx - f * 10;
    float acc = bc[co];
    const float* w = wcs + (co << 7);  // (co, ci, kt)
#pragma unroll 16
    for (int ci = 0; ci < 64; ++ci) {
      acc = fmaf(A0[ci * 96 + f], w[ci * 2 + 0], acc);
      acc = fmaf(A1[ci * 96 + f], w[ci * 2 + 1], acc);
    }
    cc[idx] = acc;
  }
  __syncthreads();
  for (int idx = tid; idx < 960; idx += 256) {
    int g = idx / 120, o = idx - g * 120;
    const float* wp = Wd + g * 7680 + o;  // Wd[g][i][o], stride 120 over i
    const float* ep = cs + (g << 6);
    float acc = 0.f;
#pragma unroll 16
    for (int i = 0; i < 64; ++i) acc = fmaf(ep[i], wp[i * 120], acc);
    out[(size_t)t * 960 + idx] = tanhf(acc) + cc[idx];
  }
}

extern "C" void kernel_launch(void* const* d_in, const int* in_sizes, int n_in,
                              void* d_out, int out_size, void* d_ws, size_t ws_size,
                              hipStream_t stream) {
  const float* emb       = (const float*)d_in[0];
  const float* c0        = (const float*)d_in[1];
  const float* lin_in_w  = (const float*)d_in[2];
  const float* w_ih      = (const float*)d_in[3];  // (2,3,512,512)
  const float* w_hh      = (const float*)d_in[4];
  const float* b_ih      = (const float*)d_in[5];  // (2,3,512)
  const float* b_hh      = (const float*)d_in[6];
  const float* skip_w    = (const float*)d_in[7];
  const float* skip_b    = (const float*)d_in[8];
  const float* lin_out_w = (const float*)d_in[9];
  const float* df_skip_w = (const float*)d_in[10];
  const float* df_skip_b = (const float*)d_in[11];
  const float* fc_a_w    = (const float*)d_in[12];
  const float* fc_a_b    = (const float*)d_in[13];
  const float* df_out_w  = (const float*)d_in[14];
  const float* convp_w   = (const float*)d_in[15];
  const float* convp_b   = (const float*)d_in[16];

  const size_t T = T_STEPS;
  float* x    = (float*)d_ws;             // T*512
  float* ih   = x + T * 512;              // T*1536
  float* h1   = ih + T * 1536;            // T*512
  ull* ring0  = (ull*)(h1 + T * 512);     // 2*512 pairs
  ull* ring1  = ring0 + 1024;             // 2*512 pairs
  float* sbuf = ih;                       // reuse ih region after scan
  float* vbuf = ih + T * 512;
  float* cbuf = ih + 2 * T * 512;
  float* outc = (float*)d_out;
  float* outa = outc + T * 960;

  // x = relu(grouped_linear(emb, lin_in_w))
  k_grouped_relu<<<T_STEPS, 256, 0, stream>>>(emb, lin_in_w, x);
  // ih0 = x @ W_ih0^T + b_ih0
  k_gemm_rr<<<dim3(128, 24), 256, 0, stream>>>(x, w_ih, b_ih, nullptr, ih, 1536);
  // fused pipelined 2-layer scan (layer0-first ordering, adjacent-pair polls)
  (void)hipMemsetAsync(ring0, 0, 2048 * sizeof(ull), stream);
  k_gru_fused<<<NWG, 512, 0, stream>>>(ih, w_hh, b_hh,
                                       w_ih + 786432, b_ih + 1536,
                                       w_hh + 786432, b_hh + 1536,
                                       h1, ring0, ring1);
  // s = h1 + x @ skip_w^T + skip_b
  k_gemm_rr<<<dim3(128, 8), 256, 0, stream>>>(x, skip_w, skip_b, h1, sbuf, 512);
  // v = relu(grouped_linear(s, lin_out_w))
  k_grouped_relu<<<T_STEPS, 256, 0, stream>>>(sbuf, lin_out_w, vbuf);
  // c = v + emb @ df_skip_w^T + df_skip_b
  k_gemm_rr<<<dim3(128, 8), 256, 0, stream>>>(emb, df_skip_w, df_skip_b, vbuf, cbuf, 512);
  // alpha = sigmoid(c @ fc_a_w^T + fc_a_b)
  k_alpha<<<T_STEPS / 4, 256, 0, stream>>>(cbuf, fc_a_w, fc_a_b, outa);
  // out = tanh(grouped_linear(c, df_out_w)) + conv(c0)
  k_dfout_conv<<<T_STEPS, 256, 0, stream>>>(cbuf, df_out_w, c0, convp_w, convp_b, outc);
  (void)in_sizes; (void)n_in; (void)out_size; (void)ws_size;
}